// Round 1
// baseline (1487.722 us; speedup 1.0000x reference)
//
#include <hip/hip_runtime.h>

#define N_NODES 100000
#define N_EDGES 1200000
#define DIM     64
#define N_LAYERS 3
#define N_GRAPHS 512
#define OUTD    192   // 3 * 64, concat layout
#define BN_EPS  1e-5f

// ---------------------------------------------------------------------------
// Transpose W2 (per layer) so the second GEMM's inner loop reads contiguous,
// wave-uniform rows (compiler scalarizes to s_load).
__global__ void transpose_w2(const float* __restrict__ W2, float* __restrict__ W2T) {
    int idx = blockIdx.x * blockDim.x + threadIdx.x;  // L*64*64
    if (idx >= N_LAYERS * DIM * DIM) return;
    int l = idx / (DIM * DIM);
    int r = idx - l * (DIM * DIM);
    int j = r >> 6;      // row in W2
    int k = r & 63;      // col in W2
    W2T[l * DIM * DIM + k * DIM + j] = W2[idx];
}

// ---------------------------------------------------------------------------
// Edge scatter: one wave per edge, lane d handles dim d.
// Gather x[src]*w (coalesced 256B row read), atomicAdd into agg[dst].
__global__ void scatter_kernel(const float* __restrict__ x, int xstride,
                               const int* __restrict__ src_idx,
                               const int* __restrict__ dst_idx,
                               const float* __restrict__ ew,
                               float* __restrict__ agg) {
    int gid = blockIdx.x * blockDim.x + threadIdx.x;
    int e = gid >> 6;
    int d = threadIdx.x & 63;
    if (e >= N_EDGES) return;
    int s = src_idx[e];
    int t = dst_idx[e];
    float w = ew[e];
    float v = w * x[(size_t)s * xstride + d];
    atomicAdd(&agg[(size_t)t * DIM + d], v);
}

// ---------------------------------------------------------------------------
// GIN MLP: h = relu( relu((agg + x) @ W1^T + b1) @ W2^T + b2 )
// One node per thread. x-row and 64 accumulators live in VGPRs; weight
// indices are wave-uniform -> scalar loads on the SMEM pipe, overlapping the
// v_fma stream. Writes pre-BN h to the xs output slot (stride OUTD).
__global__ void __launch_bounds__(256) mlp_kernel(
    const float* __restrict__ agg, const float* __restrict__ x, int xstride,
    const float* __restrict__ W1, const float* __restrict__ b1,
    const float* __restrict__ W2T, const float* __restrict__ b2,
    float* __restrict__ out /* xs base + layer*64, row stride OUTD */) {
    int n = blockIdx.x * blockDim.x + threadIdx.x;
    if (n >= N_NODES) return;

    const float4* ag4 = (const float4*)(agg + (size_t)n * DIM);
    const float4* xr4 = (const float4*)(x + (size_t)n * xstride);

    float4 xin[16];
#pragma unroll
    for (int k = 0; k < 16; ++k) {
        float4 a = ag4[k];
        float4 b = xr4[k];
        xin[k] = make_float4(a.x + b.x, a.y + b.y, a.z + b.z, a.w + b.w);
    }

    float4 acc[16];
#pragma unroll
    for (int q = 0; q < 16; ++q) acc[q] = ((const float4*)b2)[q];

    for (int j = 0; j < DIM; j += 2) {   // hidden dim, unroll 2 for ILP
        float a0 = b1[j];
        float a1 = b1[j + 1];
        const float4* w1r0 = (const float4*)(W1 + (size_t)j * DIM);
        const float4* w1r1 = (const float4*)(W1 + (size_t)(j + 1) * DIM);
#pragma unroll
        for (int k = 0; k < 16; ++k) {
            float4 w0 = w1r0[k];
            float4 w1 = w1r1[k];
            float4 xv = xin[k];
            a0 += xv.x * w0.x + xv.y * w0.y + xv.z * w0.z + xv.w * w0.w;
            a1 += xv.x * w1.x + xv.y * w1.y + xv.z * w1.z + xv.w * w1.w;
        }
        a0 = fmaxf(a0, 0.0f);
        a1 = fmaxf(a1, 0.0f);
        const float4* w2r0 = (const float4*)(W2T + (size_t)j * DIM);
        const float4* w2r1 = (const float4*)(W2T + (size_t)(j + 1) * DIM);
#pragma unroll
        for (int q = 0; q < 16; ++q) {
            float4 w0 = w2r0[q];
            float4 w1 = w2r1[q];
            acc[q].x += a0 * w0.x + a1 * w1.x;
            acc[q].y += a0 * w0.y + a1 * w1.y;
            acc[q].z += a0 * w0.z + a1 * w1.z;
            acc[q].w += a0 * w0.w + a1 * w1.w;
        }
    }

    float* orow = out + (size_t)n * OUTD;
#pragma unroll
    for (int q = 0; q < 16; ++q) {
        float4 v = acc[q];
        v.x = fmaxf(v.x, 0.0f);
        v.y = fmaxf(v.y, 0.0f);
        v.z = fmaxf(v.z, 0.0f);
        v.w = fmaxf(v.w, 0.0f);
        ((float4*)orow)[q] = v;
    }
}

// ---------------------------------------------------------------------------
// BN statistics: per-dim sum and sumsq over all nodes (double accumulators).
// Lane d of each wave handles dim d; waves stride over nodes (coalesced rows).
__global__ void stats_kernel(const float* __restrict__ h /* xs + layer*64 */,
                             double* __restrict__ ssum, double* __restrict__ ssq) {
    int gid = blockIdx.x * blockDim.x + threadIdx.x;
    int d = gid & 63;
    int w = gid >> 6;
    int nw = (gridDim.x * blockDim.x) >> 6;
    double s = 0.0, s2 = 0.0;
    for (int n = w; n < N_NODES; n += nw) {
        float v = h[(size_t)n * OUTD + d];
        s += (double)v;
        s2 += (double)v * (double)v;
    }
    atomicAdd(&ssum[d], s);
    atomicAdd(&ssq[d], s2);
}

// Fold stats + gamma/beta into per-dim scale/shift.
__global__ void bn_prep(const double* __restrict__ ssum, const double* __restrict__ ssq,
                        const float* __restrict__ gamma, const float* __restrict__ beta,
                        float* __restrict__ scale, float* __restrict__ shift) {
    int d = threadIdx.x;  // 64
    double mu = ssum[d] / (double)N_NODES;
    double var = ssq[d] / (double)N_NODES - mu * mu;
    float inv = (float)(1.0 / sqrt(var + (double)BN_EPS));
    float sc = gamma[d] * inv;
    scale[d] = sc;
    shift[d] = beta[d] - (float)mu * sc;
}

// Apply BN in-place in the xs slot (float4 over the 64-dim layer block).
__global__ void bn_kernel(float* __restrict__ h /* xs + layer*64 */,
                          const float* __restrict__ scale,
                          const float* __restrict__ shift) {
    int idx = blockIdx.x * blockDim.x + threadIdx.x;  // N_NODES * 16
    if (idx >= N_NODES * 16) return;
    int n = idx >> 4;
    int q = idx & 15;
    float* p = h + (size_t)n * OUTD + q * 4;
    float4 v = *(float4*)p;
    float4 sc = ((const float4*)scale)[q];
    float4 sh = ((const float4*)shift)[q];
    v.x = v.x * sc.x + sh.x;
    v.y = v.y * sc.y + sh.y;
    v.z = v.z * sc.z + sh.z;
    v.w = v.w * sc.w + sh.w;
    *(float4*)p = v;
}

// ---------------------------------------------------------------------------
// Add-pool per graph. batch is sorted -> binary-search segment bounds.
// One block per graph, 192 threads (one per output dim), coalesced row reads.
__global__ void pool_kernel(const float* __restrict__ xs,
                            const int* __restrict__ batch,
                            float* __restrict__ pooled) {
    int g = blockIdx.x;
    int d = threadIdx.x;  // 0..191
    int start, end;
    {
        int l = 0, h = N_NODES;
        while (l < h) { int m = (l + h) >> 1; if (batch[m] < g) l = m + 1; else h = m; }
        start = l;
    }
    {
        int l = start, h = N_NODES;
        while (l < h) { int m = (l + h) >> 1; if (batch[m] <= g) l = m + 1; else h = m; }
        end = l;
    }
    float acc = 0.0f;
    for (int n = start; n < end; ++n) acc += xs[(size_t)n * OUTD + d];
    pooled[(size_t)g * OUTD + d] = acc;
}

// ---------------------------------------------------------------------------
extern "C" void kernel_launch(void* const* d_in, const int* in_sizes, int n_in,
                              void* d_out, int out_size, void* d_ws, size_t ws_size,
                              hipStream_t stream) {
    const float* x0    = (const float*)d_in[0];
    const int*   ei    = (const int*)d_in[1];
    const float* ew    = (const float*)d_in[2];
    const int*   batch = (const int*)d_in[3];
    // d_in[4] = pool scalar (0 = add) — static in reference
    const float* W1    = (const float*)d_in[5];
    const float* b1    = (const float*)d_in[6];
    const float* W2    = (const float*)d_in[7];
    const float* b2    = (const float*)d_in[8];
    const float* gamma = (const float*)d_in[9];
    const float* beta  = (const float*)d_in[10];

    float* pooled = (float*)d_out;                      // [512, 192]
    float* xs     = pooled + (size_t)N_GRAPHS * OUTD;   // [100000, 192]

    // Workspace layout (all offsets 16B-aligned):
    float*  agg  = (float*)d_ws;                         // N*64 floats (25.6 MB)
    float*  W2T  = agg + (size_t)N_NODES * DIM;          // 3*64*64 floats
    double* ssum = (double*)(W2T + N_LAYERS * DIM * DIM);// 64 doubles
    double* ssq  = ssum + DIM;                           // 64 doubles
    float*  scale = (float*)(ssq + DIM);                 // 64 floats
    float*  shift = scale + DIM;                         // 64 floats

    const int* src = ei;
    const int* dst = ei + N_EDGES;

    transpose_w2<<<(N_LAYERS * DIM * DIM + 255) / 256, 256, 0, stream>>>(W2, W2T);

    for (int i = 0; i < N_LAYERS; ++i) {
        const float* xin = (i == 0) ? x0 : (xs + (size_t)(i - 1) * DIM);
        int xstride = (i == 0) ? DIM : OUTD;

        hipMemsetAsync(agg, 0, (size_t)N_NODES * DIM * sizeof(float), stream);
        hipMemsetAsync(ssum, 0, 2 * DIM * sizeof(double), stream);

        scatter_kernel<<<(N_EDGES * 64) / 256, 256, 0, stream>>>(
            xin, xstride, src, dst, ew, agg);

        mlp_kernel<<<(N_NODES + 255) / 256, 256, 0, stream>>>(
            agg, xin, xstride,
            W1 + (size_t)i * DIM * DIM, b1 + (size_t)i * DIM,
            W2T + (size_t)i * DIM * DIM, b2 + (size_t)i * DIM,
            xs + (size_t)i * DIM);

        stats_kernel<<<256, 256, 0, stream>>>(xs + (size_t)i * DIM, ssum, ssq);
        bn_prep<<<1, 64, 0, stream>>>(ssum, ssq, gamma + (size_t)i * DIM,
                                      beta + (size_t)i * DIM, scale, shift);
        bn_kernel<<<(N_NODES * 16 + 255) / 256, 256, 0, stream>>>(
            xs + (size_t)i * DIM, scale, shift);
    }

    pool_kernel<<<N_GRAPHS, OUTD, 0, stream>>>(xs, batch, pooled);
}

// Round 2
// 1088.922 us; speedup vs baseline: 1.3662x; 1.3662x over previous
//
#include <hip/hip_runtime.h>

#define N_NODES 100000
#define N_EDGES 1200000
#define DIM     64
#define N_LAYERS 3
#define N_GRAPHS 512
#define OUTD    192   // 3 * 64, concat layout
#define BN_EPS  1e-5f

#define SCAN_CHUNK 1024                       // elements per scan block
#define NBLK ((N_NODES + SCAN_CHUNK - 1) / SCAN_CHUNK)   // 98

// ---------------------------------------------------------------------------
// Transpose W2 (per layer) so the second GEMM's inner loop reads contiguous,
// wave-uniform rows.
__global__ void transpose_w2(const float* __restrict__ W2, float* __restrict__ W2T) {
    int idx = blockIdx.x * blockDim.x + threadIdx.x;  // L*64*64
    if (idx >= N_LAYERS * DIM * DIM) return;
    int l = idx / (DIM * DIM);
    int r = idx - l * (DIM * DIM);
    int j = r >> 6;      // row in W2
    int k = r & 63;      // col in W2
    W2T[l * DIM * DIM + k * DIM + j] = W2[idx];
}

// ---------------------------------------------------------------------------
// Counting-sort of edges by dst (built ONCE per call; reused by all 3 layers).
// 1) histogram of dst
__global__ void hist_kernel(const int* __restrict__ dst, int* __restrict__ counts) {
    int e = blockIdx.x * blockDim.x + threadIdx.x;
    if (e >= N_EDGES) return;
    atomicAdd(&counts[dst[e]], 1);
}

// 2a) per-block partial sums of counts
__global__ void scan_partial(const int* __restrict__ C, int* __restrict__ bsum) {
    __shared__ int lds[256];
    int b = blockIdx.x, t = threadIdx.x;
    int base = b * SCAN_CHUNK + t * 4;
    int s = 0;
#pragma unroll
    for (int k = 0; k < 4; ++k) {
        int i = base + k;
        if (i < N_NODES) s += C[i];
    }
    lds[t] = s;
    __syncthreads();
    for (int o = 128; o > 0; o >>= 1) {
        if (t < o) lds[t] += lds[t + o];
        __syncthreads();
    }
    if (t == 0) bsum[b] = lds[0];
}

// 2b) exclusive scan of the 98 block sums (single block)
__global__ void scan_bsum(int* __restrict__ bsum) {
    __shared__ int lds[128];
    int t = threadIdx.x;
    int v = (t < NBLK) ? bsum[t] : 0;
    lds[t] = v;
    __syncthreads();
    for (int o = 1; o < 128; o <<= 1) {
        int add = (t >= o) ? lds[t - o] : 0;
        __syncthreads();
        lds[t] += add;
        __syncthreads();
    }
    if (t < NBLK) bsum[t] = lds[t] - v;   // exclusive
}

// 2c) final offsets: O[i] (exclusive, N_NODES+1 entries) and cursor copy.
__global__ void scan_final(const int* __restrict__ C, const int* __restrict__ bsum,
                           int* __restrict__ O, int* __restrict__ cursor) {
    __shared__ int lds[256];
    int b = blockIdx.x, t = threadIdx.x;
    int base = b * SCAN_CHUNK + t * 4;
    int v[4];
    int s = 0;
#pragma unroll
    for (int k = 0; k < 4; ++k) {
        int i = base + k;
        v[k] = (i < N_NODES) ? C[i] : 0;
        s += v[k];
    }
    lds[t] = s;
    __syncthreads();
    for (int o = 1; o < 256; o <<= 1) {
        int add = (t >= o) ? lds[t - o] : 0;
        __syncthreads();
        lds[t] += add;
        __syncthreads();
    }
    int off = bsum[b] + (lds[t] - s);   // exclusive prefix for this thread
#pragma unroll
    for (int k = 0; k < 4; ++k) {
        int i = base + k;
        if (i < N_NODES) {
            O[i] = off;
            cursor[i] = off;
            off += v[k];
            if (i == N_NODES - 1) O[N_NODES] = off;
        }
    }
}

// 3) bin edges: write (src, w) into dst-sorted order
__global__ void edge_bin(const int* __restrict__ src, const int* __restrict__ dst,
                         const float* __restrict__ ew,
                         int* __restrict__ cursor,
                         int* __restrict__ ssrc, float* __restrict__ sw) {
    int e = blockIdx.x * blockDim.x + threadIdx.x;
    if (e >= N_EDGES) return;
    int t = dst[e];
    int pos = atomicAdd(&cursor[t], 1);
    ssrc[pos] = src[e];
    sw[pos] = ew[e];
}

// ---------------------------------------------------------------------------
// Aggregation (gather form, no atomics): one wave per node, lane d = dim d.
// agg[n] = x_in[n] + sum_{e in seg(n)} w_e * x_in[src_e]   (the +x is fused)
__global__ void __launch_bounds__(256) agg_kernel(
    const float* __restrict__ x_in, int xstride,
    const int* __restrict__ offsets,
    const int* __restrict__ ssrc, const float* __restrict__ sw,
    float* __restrict__ agg) {
    int gid = blockIdx.x * blockDim.x + threadIdx.x;
    int n = gid >> 6;
    int d = threadIdx.x & 63;
    if (n >= N_NODES) return;
    int beg = offsets[n];
    int end = offsets[n + 1];
    float acc = x_in[(size_t)n * xstride + d];
    for (int base = beg; base < end; base += 64) {
        int cnt = end - base;
        if (cnt > 64) cnt = 64;
        // coalesced batch load of up to 64 (src, w) pairs, then lane-broadcast
        int  sv = (d < cnt) ? ssrc[base + d] : 0;
        float wv = (d < cnt) ? sw[base + d] : 0.0f;
        for (int j = 0; j < cnt; ++j) {
            int s = __shfl(sv, j);
            float w = __shfl(wv, j);
            acc += w * x_in[(size_t)s * xstride + d];
        }
    }
    agg[(size_t)n * DIM + d] = acc;
}

// ---------------------------------------------------------------------------
// GIN MLP: h = relu( relu(hin @ W1^T + b1) @ W2^T + b2 ), hin = agg (+x fused)
// One node per thread; weights are wave-uniform -> scalar loads.
__global__ void __launch_bounds__(256) mlp_kernel(
    const float* __restrict__ hin,
    const float* __restrict__ W1, const float* __restrict__ b1,
    const float* __restrict__ W2T, const float* __restrict__ b2,
    float* __restrict__ out /* xs base + layer*64, row stride OUTD */) {
    int n = blockIdx.x * blockDim.x + threadIdx.x;
    if (n >= N_NODES) return;

    const float4* in4 = (const float4*)(hin + (size_t)n * DIM);
    float4 xin[16];
#pragma unroll
    for (int k = 0; k < 16; ++k) xin[k] = in4[k];

    float4 acc[16];
#pragma unroll
    for (int q = 0; q < 16; ++q) acc[q] = ((const float4*)b2)[q];

    for (int j = 0; j < DIM; j += 2) {
        float a0 = b1[j];
        float a1 = b1[j + 1];
        const float4* w1r0 = (const float4*)(W1 + (size_t)j * DIM);
        const float4* w1r1 = (const float4*)(W1 + (size_t)(j + 1) * DIM);
#pragma unroll
        for (int k = 0; k < 16; ++k) {
            float4 w0 = w1r0[k];
            float4 w1 = w1r1[k];
            float4 xv = xin[k];
            a0 += xv.x * w0.x + xv.y * w0.y + xv.z * w0.z + xv.w * w0.w;
            a1 += xv.x * w1.x + xv.y * w1.y + xv.z * w1.z + xv.w * w1.w;
        }
        a0 = fmaxf(a0, 0.0f);
        a1 = fmaxf(a1, 0.0f);
        const float4* w2r0 = (const float4*)(W2T + (size_t)j * DIM);
        const float4* w2r1 = (const float4*)(W2T + (size_t)(j + 1) * DIM);
#pragma unroll
        for (int q = 0; q < 16; ++q) {
            float4 w0 = w2r0[q];
            float4 w1 = w2r1[q];
            acc[q].x += a0 * w0.x + a1 * w1.x;
            acc[q].y += a0 * w0.y + a1 * w1.y;
            acc[q].z += a0 * w0.z + a1 * w1.z;
            acc[q].w += a0 * w0.w + a1 * w1.w;
        }
    }

    float* orow = out + (size_t)n * OUTD;
#pragma unroll
    for (int q = 0; q < 16; ++q) {
        float4 v = acc[q];
        v.x = fmaxf(v.x, 0.0f);
        v.y = fmaxf(v.y, 0.0f);
        v.z = fmaxf(v.z, 0.0f);
        v.w = fmaxf(v.w, 0.0f);
        ((float4*)orow)[q] = v;
    }
}

// ---------------------------------------------------------------------------
// BN statistics: per-dim sum and sumsq (double accumulators).
__global__ void stats_kernel(const float* __restrict__ h,
                             double* __restrict__ ssum, double* __restrict__ ssq) {
    int gid = blockIdx.x * blockDim.x + threadIdx.x;
    int d = gid & 63;
    int w = gid >> 6;
    int nw = (gridDim.x * blockDim.x) >> 6;
    double s = 0.0, s2 = 0.0;
    for (int n = w; n < N_NODES; n += nw) {
        float v = h[(size_t)n * OUTD + d];
        s += (double)v;
        s2 += (double)v * (double)v;
    }
    atomicAdd(&ssum[d], s);
    atomicAdd(&ssq[d], s2);
}

__global__ void bn_prep(const double* __restrict__ ssum, const double* __restrict__ ssq,
                        const float* __restrict__ gamma, const float* __restrict__ beta,
                        float* __restrict__ scale, float* __restrict__ shift) {
    int d = threadIdx.x;  // 64
    double mu = ssum[d] / (double)N_NODES;
    double var = ssq[d] / (double)N_NODES - mu * mu;
    float inv = (float)(1.0 / sqrt(var + (double)BN_EPS));
    float sc = gamma[d] * inv;
    scale[d] = sc;
    shift[d] = beta[d] - (float)mu * sc;
}

__global__ void bn_kernel(float* __restrict__ h,
                          const float* __restrict__ scale,
                          const float* __restrict__ shift) {
    int idx = blockIdx.x * blockDim.x + threadIdx.x;  // N_NODES * 16
    if (idx >= N_NODES * 16) return;
    int n = idx >> 4;
    int q = idx & 15;
    float* p = h + (size_t)n * OUTD + q * 4;
    float4 v = *(float4*)p;
    float4 sc = ((const float4*)scale)[q];
    float4 sh = ((const float4*)shift)[q];
    v.x = v.x * sc.x + sh.x;
    v.y = v.y * sc.y + sh.y;
    v.z = v.z * sc.z + sh.z;
    v.w = v.w * sc.w + sh.w;
    *(float4*)p = v;
}

// ---------------------------------------------------------------------------
// Add-pool: 4 blocks per graph (blockIdx.y = part), partial sums + one
// atomicAdd per dim per part (512*4*192 atomics, trivial). pooled pre-zeroed.
__global__ void pool_kernel(const float* __restrict__ xs,
                            const int* __restrict__ batch,
                            float* __restrict__ pooled) {
    int g = blockIdx.x;
    int part = blockIdx.y;   // 0..3
    int d = threadIdx.x;     // 0..191
    int start, end;
    {
        int l = 0, h = N_NODES;
        while (l < h) { int m = (l + h) >> 1; if (batch[m] < g) l = m + 1; else h = m; }
        start = l;
    }
    {
        int l = start, h = N_NODES;
        while (l < h) { int m = (l + h) >> 1; if (batch[m] <= g) l = m + 1; else h = m; }
        end = l;
    }
    float acc = 0.0f;
    for (int n = start + part; n < end; n += 4) acc += xs[(size_t)n * OUTD + d];
    atomicAdd(&pooled[(size_t)g * OUTD + d], acc);
}

// ---------------------------------------------------------------------------
extern "C" void kernel_launch(void* const* d_in, const int* in_sizes, int n_in,
                              void* d_out, int out_size, void* d_ws, size_t ws_size,
                              hipStream_t stream) {
    const float* x0    = (const float*)d_in[0];
    const int*   ei    = (const int*)d_in[1];
    const float* ew    = (const float*)d_in[2];
    const int*   batch = (const int*)d_in[3];
    const float* W1    = (const float*)d_in[5];
    const float* b1    = (const float*)d_in[6];
    const float* W2    = (const float*)d_in[7];
    const float* b2    = (const float*)d_in[8];
    const float* gamma = (const float*)d_in[9];
    const float* beta  = (const float*)d_in[10];

    float* pooled = (float*)d_out;                      // [512, 192]
    float* xs     = pooled + (size_t)N_GRAPHS * OUTD;   // [100000, 192]

    // Workspace layout (16B aligned blocks):
    float*  agg     = (float*)d_ws;                        // 25.6 MB
    int*    ssrc    = (int*)(agg + (size_t)N_NODES * DIM); // 4.8 MB
    float*  sw      = (float*)(ssrc + N_EDGES);            // 4.8 MB
    int*    counts  = (int*)(sw + N_EDGES);                // 400 KB
    int*    offsets = counts + N_NODES + 4;                // 400 KB (N+1)
    int*    cursor  = offsets + N_NODES + 4;               // 400 KB
    int*    bsum    = cursor + N_NODES + 4;                // 128 ints
    float*  W2T     = (float*)(bsum + 128);                // 48 KB
    double* ssum    = (double*)(W2T + N_LAYERS * DIM * DIM);
    double* ssq     = ssum + DIM;
    float*  scale   = (float*)(ssq + DIM);
    float*  shift   = scale + DIM;

    const int* src = ei;
    const int* dst = ei + N_EDGES;

    transpose_w2<<<(N_LAYERS * DIM * DIM + 255) / 256, 256, 0, stream>>>(W2, W2T);

    // --- edge counting-sort (once per call) ---
    hipMemsetAsync(counts, 0, (size_t)(N_NODES + 4) * sizeof(int), stream);
    hist_kernel<<<(N_EDGES + 255) / 256, 256, 0, stream>>>(dst, counts);
    scan_partial<<<NBLK, 256, 0, stream>>>(counts, bsum);
    scan_bsum<<<1, 128, 0, stream>>>(bsum);
    scan_final<<<NBLK, 256, 0, stream>>>(counts, bsum, offsets, cursor);
    edge_bin<<<(N_EDGES + 255) / 256, 256, 0, stream>>>(src, dst, ew, cursor, ssrc, sw);

    for (int i = 0; i < N_LAYERS; ++i) {
        const float* xin = (i == 0) ? x0 : (xs + (size_t)(i - 1) * DIM);
        int xstride = (i == 0) ? DIM : OUTD;

        hipMemsetAsync(ssum, 0, 2 * DIM * sizeof(double), stream);

        agg_kernel<<<(N_NODES * 64 + 255) / 256, 256, 0, stream>>>(
            xin, xstride, offsets, ssrc, sw, agg);

        mlp_kernel<<<(N_NODES + 255) / 256, 256, 0, stream>>>(
            agg,
            W1 + (size_t)i * DIM * DIM, b1 + (size_t)i * DIM,
            W2T + (size_t)i * DIM * DIM, b2 + (size_t)i * DIM,
            xs + (size_t)i * DIM);

        stats_kernel<<<256, 256, 0, stream>>>(xs + (size_t)i * DIM, ssum, ssq);
        bn_prep<<<1, 64, 0, stream>>>(ssum, ssq, gamma + (size_t)i * DIM,
                                      beta + (size_t)i * DIM, scale, shift);
        bn_kernel<<<(N_NODES * 16 + 255) / 256, 256, 0, stream>>>(
            xs + (size_t)i * DIM, scale, shift);
    }

    hipMemsetAsync(pooled, 0, (size_t)N_GRAPHS * OUTD * sizeof(float), stream);
    dim3 pgrid(N_GRAPHS, 4);
    pool_kernel<<<pgrid, OUTD, 0, stream>>>(xs, batch, pooled);
}

// Round 3
// 782.350 us; speedup vs baseline: 1.9016x; 1.3919x over previous
//
#include <hip/hip_runtime.h>

#define N_NODES 100000
#define N_EDGES 1200000
#define DIM     64
#define N_LAYERS 3
#define N_GRAPHS 512
#define OUTD    192   // 3 * 64, concat layout
#define BN_EPS  1e-5f

#define SCAN_CHUNK 1024
#define NBLK ((N_NODES + SCAN_CHUNK - 1) / SCAN_CHUNK)   // 98

#define NPB 64            // nodes per block in layer_kernel
#define LDS_PITCH 65      // +1 pad -> 2-way bank aliasing only (free)

// ---------------------------------------------------------------------------
// Transpose W1 and W2 (per layer): WT[l][k][j] = W[l][j][k], so the GEMM
// inner loop reads 16 contiguous wave-uniform floats (s_load_dwordx16).
__global__ void transpose_w(const float* __restrict__ W1, const float* __restrict__ W2,
                            float* __restrict__ W1T, float* __restrict__ W2T) {
    int idx = blockIdx.x * blockDim.x + threadIdx.x;  // L*64*64
    if (idx >= N_LAYERS * DIM * DIM) return;
    int l = idx >> 12;
    int r = idx & 4095;
    int j = r >> 6;
    int k = r & 63;
    int dstp = (l << 12) + k * DIM + j;
    W1T[dstp] = W1[idx];
    W2T[dstp] = W2[idx];
}

// ---------------------------------------------------------------------------
// Counting-sort of edges by dst (once per call, reused by all 3 layers).
__global__ void hist_kernel(const int* __restrict__ dst, int* __restrict__ counts) {
    int e = blockIdx.x * blockDim.x + threadIdx.x;
    if (e >= N_EDGES) return;
    atomicAdd(&counts[dst[e]], 1);
}

__global__ void scan_partial(const int* __restrict__ C, int* __restrict__ bsum) {
    __shared__ int lds[256];
    int b = blockIdx.x, t = threadIdx.x;
    int base = b * SCAN_CHUNK + t * 4;
    int s = 0;
#pragma unroll
    for (int k = 0; k < 4; ++k) {
        int i = base + k;
        if (i < N_NODES) s += C[i];
    }
    lds[t] = s;
    __syncthreads();
    for (int o = 128; o > 0; o >>= 1) {
        if (t < o) lds[t] += lds[t + o];
        __syncthreads();
    }
    if (t == 0) bsum[b] = lds[0];
}

__global__ void scan_bsum(int* __restrict__ bsum) {
    __shared__ int lds[128];
    int t = threadIdx.x;
    int v = (t < NBLK) ? bsum[t] : 0;
    lds[t] = v;
    __syncthreads();
    for (int o = 1; o < 128; o <<= 1) {
        int add = (t >= o) ? lds[t - o] : 0;
        __syncthreads();
        lds[t] += add;
        __syncthreads();
    }
    if (t < NBLK) bsum[t] = lds[t] - v;   // exclusive
}

__global__ void scan_final(const int* __restrict__ C, const int* __restrict__ bsum,
                           int* __restrict__ O, int* __restrict__ cursor) {
    __shared__ int lds[256];
    int b = blockIdx.x, t = threadIdx.x;
    int base = b * SCAN_CHUNK + t * 4;
    int v[4];
    int s = 0;
#pragma unroll
    for (int k = 0; k < 4; ++k) {
        int i = base + k;
        v[k] = (i < N_NODES) ? C[i] : 0;
        s += v[k];
    }
    lds[t] = s;
    __syncthreads();
    for (int o = 1; o < 256; o <<= 1) {
        int add = (t >= o) ? lds[t - o] : 0;
        __syncthreads();
        lds[t] += add;
        __syncthreads();
    }
    int off = bsum[b] + (lds[t] - s);
#pragma unroll
    for (int k = 0; k < 4; ++k) {
        int i = base + k;
        if (i < N_NODES) {
            O[i] = off;
            cursor[i] = off;
            off += v[k];
            if (i == N_NODES - 1) O[N_NODES] = off;
        }
    }
}

__global__ void edge_bin(const int* __restrict__ src, const int* __restrict__ dst,
                         const float* __restrict__ ew,
                         int* __restrict__ cursor,
                         int* __restrict__ ssrc, float* __restrict__ sw) {
    int e = blockIdx.x * blockDim.x + threadIdx.x;
    if (e >= N_EDGES) return;
    int t = dst[e];
    int pos = atomicAdd(&cursor[t], 1);
    ssrc[pos] = src[e];
    sw[pos] = ew[e];
}

// ---------------------------------------------------------------------------
// Fused layer: gather (agg, +x fused) -> LDS -> MLP1 -> relu -> MLP2 -> relu
// Block = 256 threads, 64 nodes. Gather: wave w aggregates nodes [w*16,w*16+16);
// node id is wave-uniform so edge (src,w) reads are scalar loads, and the
// x_in[src] row read is one coalesced 256B vector load per edge.
// GEMMs: 4 threads per node, 16 dims each -> 16 independent FMA chains,
// weights via wave-uniform s_load_dwordx16 from W1T/W2T.
__global__ void __launch_bounds__(256) layer_kernel(
    const float* __restrict__ x_in, int xstride,
    const int* __restrict__ offsets,
    const int* __restrict__ ssrc, const float* __restrict__ sw,
    const float* __restrict__ W1T, const float* __restrict__ b1,
    const float* __restrict__ W2T, const float* __restrict__ b2,
    float* __restrict__ out /* xs base + layer*64, row stride OUTD */) {
    __shared__ float lds[NPB * LDS_PITCH];
    int t = threadIdx.x;
    int lane = t & 63;
    int wid = __builtin_amdgcn_readfirstlane(t >> 6);   // wave id 0..3, SGPR
    int nbase = blockIdx.x * NPB;

    // ---- Phase 1: gather ----
    for (int nn = 0; nn < 16; ++nn) {
        int n = nbase + wid * 16 + nn;        // wave-uniform
        float acc = 0.0f;
        if (n < N_NODES) {
            int beg = offsets[n];             // s_load
            int end = offsets[n + 1];
            acc = x_in[(size_t)n * xstride + lane];   // coalesced 256B
            for (int e = beg; e < end; ++e) {
                int s = ssrc[e];              // s_load (uniform)
                float w = sw[e];              // s_load (uniform)
                acc += w * x_in[(size_t)s * xstride + lane];
            }
        }
        lds[(wid * 16 + nn) * LDS_PITCH + lane] = acc;
    }
    __syncthreads();

    // ---- Stage 1 GEMM: hidden = relu(xin @ W1^T + b1) ----
    int nl = lane;                            // local node 0..63
    int q = wid;                              // dim quarter 0..3 (uniform)
    float h[16];
#pragma unroll
    for (int jj = 0; jj < 16; ++jj) h[jj] = b1[q * 16 + jj];
#pragma unroll 4
    for (int k = 0; k < DIM; ++k) {
        float xv = lds[nl * LDS_PITCH + k];
        const float* wr = W1T + k * DIM + q * 16;   // uniform -> s_load x16
#pragma unroll
        for (int jj = 0; jj < 16; ++jj) h[jj] = fmaf(xv, wr[jj], h[jj]);
    }
#pragma unroll
    for (int jj = 0; jj < 16; ++jj) h[jj] = fmaxf(h[jj], 0.0f);
    __syncthreads();          // everyone done reading lds (xin)
#pragma unroll
    for (int jj = 0; jj < 16; ++jj) lds[nl * LDS_PITCH + q * 16 + jj] = h[jj];
    __syncthreads();

    // ---- Stage 2 GEMM: out = relu(hidden @ W2^T + b2) ----
    float o[16];
#pragma unroll
    for (int jj = 0; jj < 16; ++jj) o[jj] = b2[q * 16 + jj];
#pragma unroll 4
    for (int k = 0; k < DIM; ++k) {
        float hv = lds[nl * LDS_PITCH + k];
        const float* wr = W2T + k * DIM + q * 16;
#pragma unroll
        for (int jj = 0; jj < 16; ++jj) o[jj] = fmaf(hv, wr[jj], o[jj]);
    }
    int n = nbase + nl;
    if (n < N_NODES) {
        float* orow = out + (size_t)n * OUTD + q * 16;
#pragma unroll
        for (int jj = 0; jj < 16; jj += 4) {
            float4 v = make_float4(fmaxf(o[jj], 0.0f), fmaxf(o[jj + 1], 0.0f),
                                   fmaxf(o[jj + 2], 0.0f), fmaxf(o[jj + 3], 0.0f));
            *(float4*)(orow + jj) = v;
        }
    }
}

// ---------------------------------------------------------------------------
// BN statistics: per-dim sum and sumsq (double accumulators).
__global__ void stats_kernel(const float* __restrict__ h,
                             double* __restrict__ ssum, double* __restrict__ ssq) {
    int gid = blockIdx.x * blockDim.x + threadIdx.x;
    int d = gid & 63;
    int w = gid >> 6;
    int nw = (gridDim.x * blockDim.x) >> 6;
    double s = 0.0, s2 = 0.0;
    for (int n = w; n < N_NODES; n += nw) {
        float v = h[(size_t)n * OUTD + d];
        s += (double)v;
        s2 += (double)v * (double)v;
    }
    atomicAdd(&ssum[d], s);
    atomicAdd(&ssq[d], s2);
}

__global__ void bn_prep(const double* __restrict__ ssum, const double* __restrict__ ssq,
                        const float* __restrict__ gamma, const float* __restrict__ beta,
                        float* __restrict__ scale, float* __restrict__ shift) {
    int d = threadIdx.x;  // 64
    double mu = ssum[d] / (double)N_NODES;
    double var = ssq[d] / (double)N_NODES - mu * mu;
    float inv = (float)(1.0 / sqrt(var + (double)BN_EPS));
    float sc = gamma[d] * inv;
    scale[d] = sc;
    shift[d] = beta[d] - (float)mu * sc;
}

__global__ void bn_kernel(float* __restrict__ h,
                          const float* __restrict__ scale,
                          const float* __restrict__ shift) {
    int idx = blockIdx.x * blockDim.x + threadIdx.x;  // N_NODES * 16
    if (idx >= N_NODES * 16) return;
    int n = idx >> 4;
    int q = idx & 15;
    float* p = h + (size_t)n * OUTD + q * 4;
    float4 v = *(float4*)p;
    float4 sc = ((const float4*)scale)[q];
    float4 sh = ((const float4*)shift)[q];
    v.x = v.x * sc.x + sh.x;
    v.y = v.y * sc.y + sh.y;
    v.z = v.z * sc.z + sh.z;
    v.w = v.w * sc.w + sh.w;
    *(float4*)p = v;
}

// ---------------------------------------------------------------------------
// Add-pool: 4 blocks per graph, partial sums + one atomicAdd per dim per part.
__global__ void pool_kernel(const float* __restrict__ xs,
                            const int* __restrict__ batch,
                            float* __restrict__ pooled) {
    int g = blockIdx.x;
    int part = blockIdx.y;   // 0..3
    int d = threadIdx.x;     // 0..191
    int start, end;
    {
        int l = 0, h = N_NODES;
        while (l < h) { int m = (l + h) >> 1; if (batch[m] < g) l = m + 1; else h = m; }
        start = l;
    }
    {
        int l = start, h = N_NODES;
        while (l < h) { int m = (l + h) >> 1; if (batch[m] <= g) l = m + 1; else h = m; }
        end = l;
    }
    float acc = 0.0f;
    for (int n = start + part; n < end; n += 4) acc += xs[(size_t)n * OUTD + d];
    atomicAdd(&pooled[(size_t)g * OUTD + d], acc);
}

// ---------------------------------------------------------------------------
extern "C" void kernel_launch(void* const* d_in, const int* in_sizes, int n_in,
                              void* d_out, int out_size, void* d_ws, size_t ws_size,
                              hipStream_t stream) {
    const float* x0    = (const float*)d_in[0];
    const int*   ei    = (const int*)d_in[1];
    const float* ew    = (const float*)d_in[2];
    const int*   batch = (const int*)d_in[3];
    const float* W1    = (const float*)d_in[5];
    const float* b1    = (const float*)d_in[6];
    const float* W2    = (const float*)d_in[7];
    const float* b2    = (const float*)d_in[8];
    const float* gamma = (const float*)d_in[9];
    const float* beta  = (const float*)d_in[10];

    float* pooled = (float*)d_out;                      // [512, 192]
    float* xs     = pooled + (size_t)N_GRAPHS * OUTD;   // [100000, 192]

    // Workspace layout:
    int*    ssrc    = (int*)d_ws;                          // 4.8 MB
    float*  sw      = (float*)(ssrc + N_EDGES);            // 4.8 MB
    int*    counts  = (int*)(sw + N_EDGES);                // 400 KB
    int*    offsets = counts + N_NODES + 4;                // 400 KB (N+1)
    int*    cursor  = offsets + N_NODES + 4;               // 400 KB
    int*    bsum    = cursor + N_NODES + 4;                // 128 ints
    float*  W1T     = (float*)(bsum + 128);                // 48 KB
    float*  W2T     = W1T + N_LAYERS * DIM * DIM;          // 48 KB
    double* ssum    = (double*)(W2T + N_LAYERS * DIM * DIM);
    double* ssq     = ssum + DIM;
    float*  scale   = (float*)(ssq + DIM);
    float*  shift   = scale + DIM;

    const int* src = ei;
    const int* dst = ei + N_EDGES;

    transpose_w<<<(N_LAYERS * DIM * DIM + 255) / 256, 256, 0, stream>>>(W1, W2, W1T, W2T);

    // --- edge counting-sort (once per call) ---
    hipMemsetAsync(counts, 0, (size_t)(N_NODES + 4) * sizeof(int), stream);
    hist_kernel<<<(N_EDGES + 255) / 256, 256, 0, stream>>>(dst, counts);
    scan_partial<<<NBLK, 256, 0, stream>>>(counts, bsum);
    scan_bsum<<<1, 128, 0, stream>>>(bsum);
    scan_final<<<NBLK, 256, 0, stream>>>(counts, bsum, offsets, cursor);
    edge_bin<<<(N_EDGES + 255) / 256, 256, 0, stream>>>(src, dst, ew, cursor, ssrc, sw);

    int nblocks = (N_NODES + NPB - 1) / NPB;   // 1563
    for (int i = 0; i < N_LAYERS; ++i) {
        const float* xin = (i == 0) ? x0 : (xs + (size_t)(i - 1) * DIM);
        int xstride = (i == 0) ? DIM : OUTD;

        hipMemsetAsync(ssum, 0, 2 * DIM * sizeof(double), stream);

        layer_kernel<<<nblocks, 256, 0, stream>>>(
            xin, xstride, offsets, ssrc, sw,
            W1T + (size_t)i * DIM * DIM, b1 + (size_t)i * DIM,
            W2T + (size_t)i * DIM * DIM, b2 + (size_t)i * DIM,
            xs + (size_t)i * DIM);

        stats_kernel<<<256, 256, 0, stream>>>(xs + (size_t)i * DIM, ssum, ssq);
        bn_prep<<<1, 64, 0, stream>>>(ssum, ssq, gamma + (size_t)i * DIM,
                                      beta + (size_t)i * DIM, scale, shift);
        bn_kernel<<<(N_NODES * 16 + 255) / 256, 256, 0, stream>>>(
            xs + (size_t)i * DIM, scale, shift);
    }

    hipMemsetAsync(pooled, 0, (size_t)N_GRAPHS * OUTD * sizeof(float), stream);
    dim3 pgrid(N_GRAPHS, 4);
    pool_kernel<<<pgrid, OUTD, 0, stream>>>(xs, batch, pooled);
}